// Round 22
// baseline (192.611 us; speedup 1.0000x reference)
//
#include <hip/hip_runtime.h>
#include <hip/hip_bf16.h>

#define NB 512
#define WD 256
#define NF 128

typedef __attribute__((ext_vector_type(8))) short short8v;
typedef __attribute__((ext_vector_type(4))) float f32x4;

__device__ inline unsigned pk2bf(float a, float b) {
  __hip_bfloat162 h;
  h.x = __float2bfloat16(a);
  h.y = __float2bfloat16(b);
  unsigned r;
  __builtin_memcpy(&r, &h, 4);
  return r;
}

__device__ inline float bf2f(unsigned short u) {
  unsigned v = (unsigned)u << 16;
  float f;
  __builtin_memcpy(&f, &v, 4);
  return f;
}

__device__ inline __hip_bfloat16 bfbits(unsigned short u) {
  __hip_bfloat16 h;
  __builtin_memcpy(&h, &u, 2);
  return h;
}

// ---------------- prep: read X f32 once -> flat bf16 + transposed bf16 ----------------
__global__ __launch_bounds__(256) void prep_x(
    const float* __restrict__ X, __hip_bfloat16* __restrict__ Xflat,
    __hip_bfloat16* __restrict__ Xt)
{
  __shared__ float tile[32][33];
  int b = blockIdx.y, tt = blockIdx.x;
  int i0 = (tt >> 3) * 32, l0 = (tt & 7) * 32;
  const float* Xb = X + (size_t)b * 32768;
  __hip_bfloat16* Fb = Xflat + (size_t)b * 32768;
  __hip_bfloat16* Tb = Xt + (size_t)b * 32768;
  int t = threadIdx.x;
  {
    int r = t >> 3, c4 = t & 7;
    float4 v = *(const float4*)(Xb + (size_t)(i0 + r) * 256 + l0 + c4 * 4);
    uint2 p;
    p.x = pk2bf(v.x, v.y);
    p.y = pk2bf(v.z, v.w);
    *(uint2*)(Fb + (size_t)(i0 + r) * 256 + l0 + c4 * 4) = p;
    tile[r][c4 * 4 + 0] = v.x;
    tile[r][c4 * 4 + 1] = v.y;
    tile[r][c4 * 4 + 2] = v.z;
    tile[r][c4 * 4 + 3] = v.w;
  }
  __syncthreads();
  {
    int cr = t >> 3, ch = t & 7;
    float a0 = tile[ch * 4 + 0][cr];
    float a1 = tile[ch * 4 + 1][cr];
    float a2 = tile[ch * 4 + 2][cr];
    float a3 = tile[ch * 4 + 3][cr];
    uint2 q;
    q.x = pk2bf(a0, a1);
    q.y = pk2bf(a2, a3);
    *(uint2*)(Tb + (size_t)(l0 + cr) * 128 + i0 + ch * 4) = q;
  }
}

// Wc[o][k*128+i] = bf16(conv_w[o][i][k])
__global__ void wc_cast(const float* __restrict__ W, __hip_bfloat16* __restrict__ Wc)
{
  int idx = blockIdx.x * 256 + threadIdx.x;  // 128*384
  int o = idx / 384, rem = idx - o * 384;
  int k = rem >> 7, i = rem & 127;
  Wc[idx] = __float2bfloat16(W[(size_t)o * 384 + i * 3 + k]);
}

// ---------------- conv as MFMA GEMM ----------------
__global__ __launch_bounds__(256) void conv_gemm(
    const __hip_bfloat16* __restrict__ Xt, const __hip_bfloat16* __restrict__ Wc,
    const float* __restrict__ bias, __hip_bfloat16* __restrict__ Out)
{
  __shared__ unsigned short ldsA[2][4096];
  __shared__ unsigned short ldsB[2][4096];
  int b = blockIdx.y;
  int trt = blockIdx.x;  // l-tile 0..1
  int t = threadIdx.x, l = t & 63, w = t >> 6;
  int wr = (w >> 1) * 64, wcc = (w & 1) * 64;
  int lr = l & 15, lg = l >> 4;
  const __hip_bfloat16* Ab = Xt + (size_t)b * 32768;
  f32x4 acc[4][4] = {};

#define CSTAGE(buf, ks)                                                               \
  {                                                                                   \
    int kgrp = (ks) >> 2;                                                             \
    int kk = ((ks) & 3) * 32 + lg * 8;                                                \
    _Pragma("unroll") for (int ff = 0; ff < 2; ++ff) {                                \
      int f = 2 * w + ff;                                                             \
      int lrow = trt * 128 + f * 16 + lr + 2 * kgrp - 4;                              \
      uint4 ga = make_uint4(0, 0, 0, 0);                                              \
      if (lrow >= 0) ga = *(const uint4*)(Ab + (size_t)lrow * 128 + kk);              \
      *(uint4*)&ldsA[buf][f * 512 + l * 8] = ga;                                      \
      *(uint4*)&ldsB[buf][f * 512 + l * 8] =                                          \
          *(const uint4*)(Wc + (size_t)(f * 16 + lr) * 384 + (ks) * 32 + lg * 8);     \
    }                                                                                 \
  }

  CSTAGE(0, 0)
  __syncthreads();
  for (int ks = 0; ks < 12; ++ks) {
    int buf = ks & 1;
    if (ks + 1 < 12) CSTAGE((ks + 1) & 1, ks + 1)
    short8v a[4], bq[4];
#pragma unroll
    for (int i = 0; i < 4; ++i)
      a[i] = *(const short8v*)&ldsA[buf][((wr >> 4) + i) * 512 + l * 8];
#pragma unroll
    for (int j = 0; j < 4; ++j)
      bq[j] = *(const short8v*)&ldsB[buf][((wcc >> 4) + j) * 512 + l * 8];
#pragma unroll
    for (int i = 0; i < 4; ++i)
#pragma unroll
      for (int j = 0; j < 4; ++j)
        acc[i][j] = __builtin_amdgcn_mfma_f32_16x16x32_bf16(a[i], bq[j], acc[i][j], 0, 0, 0);
    __syncthreads();
  }

  __hip_bfloat16* Ob = Out + (size_t)b * 32768;
#pragma unroll
  for (int i = 0; i < 4; ++i) {
#pragma unroll
    for (int j = 0; j < 4; ++j) {
      int r = trt * 128 + wr + i * 16 + lg * 4;  // l
      int c = wcc + j * 16 + lr;                 // o
      f32x4 v = acc[i][j];
      float bv = bias[c];
      uint2 p;
      p.x = pk2bf(v[0] + bv, v[1] + bv);
      p.y = pk2bf(v[2] + bv, v[3] + bv);
      *(uint2*)(Ob + (size_t)c * 256 + r) = p;
    }
  }
}

// ------- MFMA gram + softmax + batch-group accumulation (gload_lds staging) -------
// R21 spill fix: sumA kept as PACKED bf16 pairs (32 regs instead of 64) — the
// compiler's hard 124-VGPR cap for 512-thread kernels can't hold acc[64]+sumA[64];
// packed accumulation brings the live set to ~111 regs. Partials are bf16 anyway,
// so the final write is a direct bit-store; accumulation rounding adds ~2e-4 to A.
template <int N, int D, int BPG>
__global__ __launch_bounds__(512, 1) void gram_acc(
    const __hip_bfloat16* __restrict__ X, const float* __restrict__ Wq,
    const float* __restrict__ Wk, __hip_bfloat16* __restrict__ partial, float scale)
{
  constexpr int NT = N / 16;
  constexpr int C8 = D / 8;
  constexpr int KS = D / 32;
  __shared__ char lds[2][N * D * 2];  // 2 x 64KB
  __shared__ float ldsD[N];
  int t = threadIdx.x, l = t & 63, w = t >> 6;  // 8 waves
  int lr = l & 15, lg = l >> 4;
  int rowbase = blockIdx.x * 128 + w * 16;
  int swz = (lr & 7) << 4;

  if (t < N) ldsD[t] = Wk[(size_t)t * (N + 1)] * scale;
  float dqr[4];
#pragma unroll
  for (int i = 0; i < 4; ++i) dqr[i] = Wq[(size_t)(rowbase + lg * 4 + i) * (N + 1)];

  unsigned sumP[4][NT / 2] = {};  // packed bf16 pairs

#define GSTAGE(buf, gb)                                                             \
  {                                                                                 \
    const __hip_bfloat16* Xb_ = (gb);                                               \
    _Pragma("unroll") for (int c = 0; c < 8; ++c) {                                 \
      int chunk = c * 512 + t;                                                      \
      int row_ = chunk / C8, j_ = chunk % C8;                                       \
      int gsrc = row_ * D + ((j_ ^ (row_ & 7)) << 3);                               \
      __builtin_amdgcn_global_load_lds(                                             \
          (const __attribute__((address_space(1))) unsigned int*)(const void*)(Xb_ + gsrc), \
          (__attribute__((address_space(3))) unsigned int*)(void*)(&lds[buf][chunk * 16]),  \
          16, 0, 0);                                                                \
    }                                                                               \
  }

  GSTAGE(0, X + (size_t)(blockIdx.y * BPG) * N * D)
  __syncthreads();

#pragma unroll 1
  for (int g = 0; g < BPG; ++g) {
    if (g + 1 < BPG) GSTAGE((g + 1) & 1, X + (size_t)(blockIdx.y * BPG + g + 1) * N * D)
    const char* cur = lds[g & 1];

    f32x4 acc[NT] = {};
#pragma unroll
    for (int ks = 0; ks < KS; ++ks) {
      int coff = (ks * 64 + lg * 16) ^ swz;
      short8v a = *(const short8v*)(cur + (rowbase + lr) * (2 * D) + coff);
#pragma unroll
      for (int m = 0; m < NT; ++m) {
        short8v bb = *(const short8v*)(cur + (m * 16 + lr) * (2 * D) + coff);
        acc[m] = __builtin_amdgcn_mfma_f32_16x16x32_bf16(a, bb, acc[m], 0, 0, 0);
      }
    }

#pragma unroll
    for (int i = 0; i < 4; ++i) {
      float v[NT];
      float mx = -3.0e38f;
#pragma unroll
      for (int m = 0; m < NT; ++m) {
        v[m] = acc[m][i] * dqr[i] * ldsD[m * 16 + lr];
        mx = fmaxf(mx, v[m]);
      }
#pragma unroll
      for (int off = 1; off < 16; off <<= 1) mx = fmaxf(mx, __shfl_xor(mx, off));
      float sum = 0.f;
#pragma unroll
      for (int m = 0; m < NT; ++m) { v[m] = __expf(v[m] - mx); sum += v[m]; }
#pragma unroll
      for (int off = 1; off < 16; off <<= 1) sum += __shfl_xor(sum, off);
      float inv = 1.0f / sum;
#pragma unroll
      for (int m2 = 0; m2 < NT / 2; ++m2) {
        unsigned p = sumP[i][m2];
        float lo = bf2f((unsigned short)(p & 0xffff)) + v[2 * m2] * inv;
        float hi = bf2f((unsigned short)(p >> 16)) + v[2 * m2 + 1] * inv;
        sumP[i][m2] = pk2bf(lo, hi);
      }
    }

    if (g + 1 < BPG) __syncthreads();
  }

  __hip_bfloat16* Pp = partial + (size_t)blockIdx.y * N * N;
#pragma unroll
  for (int i = 0; i < 4; ++i) {
    int row = rowbase + lg * 4 + i;
#pragma unroll
    for (int m2 = 0; m2 < NT / 2; ++m2) {
      unsigned p = sumP[i][m2];
      Pp[(size_t)row * N + (2 * m2) * 16 + lr] = bfbits((unsigned short)(p & 0xffff));
      Pp[(size_t)row * N + (2 * m2 + 1) * 16 + lr] = bfbits((unsigned short)(p >> 16));
    }
  }
}

// ------- merged level-1 group reduction (both branches, GS=16) -------
__global__ __launch_bounds__(256) void reduce_g2(
    const __hip_bfloat16* __restrict__ pf, const __hip_bfloat16* __restrict__ pt,
    float* __restrict__ l2f, float* __restrict__ l2t)
{
  int bid = blockIdx.x;
  const __hip_bfloat16* partial;
  float* l2;
  int NN, bx, gy;
  if (bid < 128) { partial = pf; l2 = l2f; NN = 16384; bx = bid & 7; gy = bid >> 3; }
  else { int r2 = bid - 128; partial = pt; l2 = l2t; NN = 65536; bx = r2 & 31; gy = r2 >> 5; }
  int idx = (bx * 256 + threadIdx.x) * 8;
  const __hip_bfloat16* p = partial + (size_t)gy * 16 * NN + idx;
  float a[8] = {};
#pragma unroll 4
  for (int g = 0; g < 16; ++g) {
    uint4 u = *(const uint4*)(p + (size_t)g * NN);
    unsigned arr[4] = {u.x, u.y, u.z, u.w};
#pragma unroll
    for (int q = 0; q < 4; ++q) {
      a[2 * q] += bf2f((unsigned short)(arr[q] & 0xffff));
      a[2 * q + 1] += bf2f((unsigned short)(arr[q] >> 16));
    }
  }
  float* dst = l2 + (size_t)gy * NN + idx;
  *(float4*)dst = make_float4(a[0], a[1], a[2], a[3]);
  *(float4*)(dst + 4) = make_float4(a[4], a[5], a[6], a[7]);
}

// ------- merged final mean (both branches): A = (1/512) sum_g l2[g] -------
__global__ __launch_bounds__(256) void A_fin2(
    const float* __restrict__ l2f, const float* __restrict__ l2t,
    float* __restrict__ A1f, float* __restrict__ A1t,
    float* __restrict__ A2f, float* __restrict__ A2t)
{
  int bid = blockIdx.x;
  const float* src;
  float *A1, *A2;
  int NN, G, ib;
  if (bid < 16) { src = l2f; A1 = A1f; A2 = A2f; NN = 16384; G = 16; ib = bid; }
  else { src = l2t; A1 = A1t; A2 = A2t; NN = 65536; G = 8; ib = bid - 16; }
  int idx = (ib * 256 + threadIdx.x) * 4;
  float4 a = make_float4(0.f, 0.f, 0.f, 0.f);
  for (int g = 0; g < G; ++g) {
    float4 v = *(const float4*)(src + (size_t)g * NN + idx);
    a.x += v.x; a.y += v.y; a.z += v.z; a.w += v.w;
  }
  a.x *= (1.0f / NB); a.y *= (1.0f / NB); a.z *= (1.0f / NB); a.w *= (1.0f / NB);
  *(float4*)(A1 + idx) = a;
  *(float4*)(A2 + idx) = a;
}

// ------- dis for both branches -------
__global__ __launch_bounds__(256) void deg_both(
    const float* __restrict__ Af, const float* __restrict__ At,
    float* __restrict__ disf, float* __restrict__ dist)
{
  __shared__ float red[4][64];
  int bid = blockIdx.x;  // 0..1 feat, 2..5 time
  int branch = bid >= 2;
  int N = branch ? 256 : 128;
  const float* A = branch ? At : Af;
  float* dis = branch ? dist : disf;
  int cb = (branch ? (bid - 2) : bid) * 64;
  int t = threadIdx.x, lane = t & 63, rg = t >> 6;
  float s = 0.f;
  for (int r = rg; r < N; r += 4) s += A[(size_t)r * N + cb + lane];
  red[rg][lane] = s;
  __syncthreads();
  if (t < 64) {
    float d = red[0][t] + red[1][t] + red[2][t] + red[3][t];
    dis[cb + t] = (d > 0.f) ? (1.0f / sqrtf(d)) : 0.0f;
  }
}

// ------- one matvec stage (both branches): a[r] = dis[r]*sum_c A[r,c] v[c] -------
__global__ __launch_bounds__(256) void mv_both(
    const float* __restrict__ Af, const float* __restrict__ At,
    const float* __restrict__ vf, const float* __restrict__ vt,
    const float* __restrict__ disf, const float* __restrict__ dist,
    float* __restrict__ aof, float* __restrict__ aot,
    float* __restrict__ wof, float* __restrict__ wot, int doScale)
{
  int bid = blockIdx.x;  // 0..31 feat (128 rows), 32..95 time (256 rows)
  int branch = bid >= 32;
  int N = branch ? 256 : 128;
  const float* A = branch ? At : Af;
  const float* v = branch ? vt : vf;
  const float* dis = branch ? dist : disf;
  float* ao = branch ? aot : aof;
  float* wo = branch ? wot : wof;
  int r = (branch ? (bid - 32) : bid) * 4 + (threadIdx.x >> 6);
  int lane = threadIdx.x & 63;
  const float* Ar = A + (size_t)r * N;
  float s = 0.f;
  for (int c = lane * 4; c < N; c += 256) {
    float4 av = *(const float4*)(Ar + c);
    s += av.x * v[c] + av.y * v[c + 1] + av.z * v[c + 2] + av.w * v[c + 3];
  }
#pragma unroll
  for (int off = 32; off > 0; off >>= 1) s += __shfl_xor(s, off);
  if (lane == 0) {
    float a = dis[r] * s;
    float scale = doScale ? (branch ? (1.0f / 256.0f) : (1.0f / 128.0f)) : 1.0f;
    ao[r] = a * scale;
    wo[r] = dis[r] * a;
  }
}

// ------- fixed-order sum of a-vector (both branches) -> sv[branch*2+idx] -------
__global__ __launch_bounds__(256) void sum_both(
    const float* __restrict__ af, const float* __restrict__ at,
    float* __restrict__ sv, int idx)
{
  __shared__ float part[4];
  int branch = blockIdx.x;
  int N = branch ? 256 : 128;
  const float* a = branch ? at : af;
  int t = threadIdx.x, lane = t & 63, w = t >> 6;
  float x = (t < N) ? a[t] : 0.f;
#pragma unroll
  for (int off = 32; off > 0; off >>= 1) x += __shfl_xor(x, off);
  if (lane == 0) part[w] = x;
  __syncthreads();
  if (t == 0) sv[branch * 2 + idx] = part[0] + part[1] + part[2] + part[3];
}

// ------- parallel Q-chain stage: C[M][64] = A[M][128] * B[128][64] -------
__global__ __launch_bounds__(256) void qchain(
    const float* __restrict__ Af, const float* __restrict__ At,
    const float* __restrict__ Bf, const float* __restrict__ Bt,
    float* __restrict__ Cf, float* __restrict__ Ct, int Mf, int Mt)
{
  int branch = blockIdx.y;
  const float* A = branch ? At : Af;
  const float* B = branch ? Bt : Bf;
  float* C = branch ? Ct : Cf;
  int M = branch ? Mt : Mf;
  int r = blockIdx.x * 4 + (threadIdx.x >> 6);
  int o = threadIdx.x & 63;
  if (r >= M) return;
  const float* Ar = A + (size_t)r * 128;
  float s = 0.f;
#pragma unroll 8
  for (int k = 0; k < 128; k += 4) {
    float4 wv = *(const float4*)(Ar + k);
    s += wv.x * B[k * 64 + o] + wv.y * B[(k + 1) * 64 + o] +
         wv.z * B[(k + 2) * 64 + o] + wv.w * B[(k + 3) * 64 + o];
  }
  C[(size_t)r * 64 + o] = s;
}

// ------- bias fold: cb[branch] = cf' P, cf = (s2 b1'W2W3 + s1 b2'W3)/N + b3 -------
__global__ __launch_bounds__(128) void bias_fold(
    const float* __restrict__ gf1b, const float* __restrict__ gf2w, const float* __restrict__ gf2b,
    const float* __restrict__ gf3w, const float* __restrict__ gf3b,
    const float* __restrict__ gt1b, const float* __restrict__ gt2w, const float* __restrict__ gt2b,
    const float* __restrict__ gt3w, const float* __restrict__ gt3b,
    const float* __restrict__ projw, const float* __restrict__ sv,
    float* __restrict__ cb)
{
  int branch = blockIdx.x;
  int N = branch ? 256 : 128;
  const float* W2 = branch ? gt2w : gf2w;
  const float* W3 = branch ? gt3w : gf3w;
  const float* b1 = branch ? gt1b : gf1b;
  const float* b2 = branch ? gt2b : gf2b;
  const float* b3 = branch ? gt3b : gf3b;
  const float* P = projw + (size_t)branch * 128 * 64;
  float s1 = sv[branch * 2 + 0], s2 = sv[branch * 2 + 1];
  __shared__ float r1[128], cf[128];
  int t = threadIdx.x;

  {
    float s = 0.f;
#pragma unroll 4
    for (int h = 0; h < 128; ++h) s += b1[h] * W2[(size_t)h * 128 + t];
    r1[t] = s;
  }
  __syncthreads();
  {
    float sa = 0.f, sb = 0.f;
#pragma unroll 4
    for (int h = 0; h < 128; ++h) {
      float w3v = W3[(size_t)h * 128 + t];
      sa += r1[h] * w3v;
      sb += b2[h] * w3v;
    }
    cf[t] = (s2 * sa + s1 * sb) * (1.0f / N) + b3[t];
  }
  __syncthreads();
  if (t < 64) {
    float s = 0.f;
#pragma unroll 4
    for (int h = 0; h < 128; ++h) s += cf[h] * P[(size_t)h * 64 + t];
    cb[branch * 64 + t] = s;
  }
}

// ------- final: out[b] = (uf'XF[b])Qf + (ut'Xt[b])Qt + pb + cb_f + cb_t -------
__global__ __launch_bounds__(256) void gcn_out(
    const __hip_bfloat16* __restrict__ XF, const __hip_bfloat16* __restrict__ Xt,
    const float* __restrict__ uf, const float* __restrict__ ut,
    const float* __restrict__ Qf, const float* __restrict__ Qt,
    const float* __restrict__ cb, const float* __restrict__ pb,
    float* __restrict__ out)
{
  __shared__ float red[2048];
  __shared__ float yfL[256], ytL[128], red3[4][64];
  int b = blockIdx.x, t = threadIdx.x;

  {
    int rr = t >> 5, cc = t & 31;
    const __hip_bfloat16* base = XF + (size_t)b * 32768;
    float acc[8] = {};
    for (int it = 0; it < 16; ++it) {
      int row = it * 8 + rr;
      float uw = uf[row];
      uint4 v = *(const uint4*)(base + (size_t)row * 256 + cc * 8);
      unsigned arr[4] = {v.x, v.y, v.z, v.w};
#pragma unroll
      for (int q = 0; q < 4; ++q) {
        acc[2 * q] += uw * bf2f((unsigned short)(arr[q] & 0xffff));
        acc[2 * q + 1] += uw * bf2f((unsigned short)(arr[q] >> 16));
      }
    }
#pragma unroll
    for (int j = 0; j < 8; ++j) red[rr * 256 + cc * 8 + j] = acc[j];
  }
  __syncthreads();
  {
    float s = 0.f;
#pragma unroll
    for (int g = 0; g < 8; ++g) s += red[g * 256 + t];
    yfL[t] = s;
  }
  __syncthreads();
  {
    int rr = t >> 4, cc = t & 15;
    const __hip_bfloat16* base = Xt + (size_t)b * 32768;
    float acc[8] = {};
    for (int it = 0; it < 16; ++it) {
      int row = it * 16 + rr;
      float uw = ut[row];
      uint4 v = *(const uint4*)(base + (size_t)row * 128 + cc * 8);
      unsigned arr[4] = {v.x, v.y, v.z, v.w};
#pragma unroll
      for (int q = 0; q < 4; ++q) {
        acc[2 * q] += uw * bf2f((unsigned short)(arr[q] & 0xffff));
        acc[2 * q + 1] += uw * bf2f((unsigned short)(arr[q] >> 16));
      }
    }
#pragma unroll
    for (int j = 0; j < 8; ++j) red[rr * 128 + cc * 8 + j] = acc[j];
  }
  __syncthreads();
  if (t < 128) {
    float s = 0.f;
#pragma unroll
    for (int g = 0; g < 16; ++g) s += red[g * 128 + t];
    ytL[t] = s;
  }
  __syncthreads();
  {
    int grp = t >> 6, o = t & 63;
    float s = 0.f;
    for (int jj = 0; jj < 64; ++jj) {
      int j = grp * 64 + jj;
      s += yfL[j] * Qf[(size_t)j * 64 + o];
    }
    for (int jj = 0; jj < 32; ++jj) {
      int j = grp * 32 + jj;
      s += ytL[j] * Qt[(size_t)j * 64 + o];
    }
    red3[grp][o] = s;
  }
  __syncthreads();
  if (t < 64) {
    out[(size_t)b * 64 + t] = red3[0][t] + red3[1][t] + red3[2][t] + red3[3][t] +
                              pb[t] + cb[t] + cb[64 + t];
  }
}

extern "C" void kernel_launch(void* const* d_in, const int* in_sizes, int n_in,
                              void* d_out, int out_size, void* d_ws, size_t ws_size,
                              hipStream_t stream)
{
  const float* X_time = (const float*)d_in[0];
  const float* conv_w = (const float*)d_in[1];
  const float* conv_b = (const float*)d_in[2];
  const float* wq_feat = (const float*)d_in[3];
  const float* wk_feat = (const float*)d_in[4];
  const float* wq_time = (const float*)d_in[5];
  const float* wk_time = (const float*)d_in[6];
  const float* gf1_w = (const float*)d_in[7];
  const float* gf1_b = (const float*)d_in[8];
  const float* gf2_w = (const float*)d_in[9];
  const float* gf2_b = (const float*)d_in[10];
  const float* gf3_w = (const float*)d_in[11];
  const float* gf3_b = (const float*)d_in[12];
  const float* gt1_w = (const float*)d_in[13];
  const float* gt1_b = (const float*)d_in[14];
  const float* gt2_w = (const float*)d_in[15];
  const float* gt2_b = (const float*)d_in[16];
  const float* gt3_w = (const float*)d_in[17];
  const float* gt3_b = (const float*)d_in[18];
  const float* proj_w = (const float*)d_in[19];
  const float* proj_b = (const float*)d_in[20];

  typedef __hip_bfloat16 bf16;
  char* ws = (char*)d_ws;
  const size_t MiB = 1ull << 20;
  bf16* XFb = (bf16*)ws;                         // 32MB
  bf16* Xtb = (bf16*)(ws + 34 * MiB);            // 32MB
  bf16* partial_f = (bf16*)(ws + 68 * MiB);      // 8MB
  bf16* partial_t = (bf16*)(ws + 100 * MiB);     // 16MB
  bf16* Xt = (bf16*)(ws + 100 * MiB);            // 32MB, conv-only
  float* l2f = (float*)(ws + 164 * MiB);         // 1MB
  float* l2t = (float*)(ws + 166 * MiB);         // 2MB
  char* SM = ws + 171 * MiB;
  float* A_feat = (float*)SM;                    // 64KB
  float* A_time = (float*)(SM + 65536);          // 256KB
  float* uf = (float*)(SM + 327680);
  float* ut = (float*)(SM + 328704);
  float* sv = (float*)(SM + 329728);
  float* Qf = (float*)(SM + 331776);
  float* Qt = (float*)(SM + 397312);
  float* cb = (float*)(SM + 430080);
  bf16* Wcv = (bf16*)(SM + 432128);
  float* S3f = (float*)(SM + 530432);
  float* S3t = (float*)(SM + 563200);
  float* S2f = (float*)(SM + 595968);
  float* S2t = (float*)(SM + 628736);
  float* dis_f = (float*)(SM + 661504);
  float* dis_t = (float*)(SM + 662528);
  float* a1f = (float*)(SM + 663552);
  float* a1t = (float*)(SM + 664576);
  float* a2f = (float*)(SM + 665600);
  float* a2t = (float*)(SM + 666624);
  float* w1f = (float*)(SM + 667648);
  float* w1t = (float*)(SM + 668672);
  float* w2f = (float*)(SM + 669696);
  float* w2t = (float*)(SM + 670720);
  float* wdf = (float*)(SM + 671744);
  float* wdt = (float*)(SM + 672768);

  float* out = (float*)d_out;
  float* outA_f = out + 32768;
  float* outA_t = out + 49152;

  // 1) prep + conv
  prep_x<<<dim3(32, NB), 256, 0, stream>>>(X_time, Xtb, Xt);
  wc_cast<<<192, 256, 0, stream>>>(conv_w, Wcv);
  conv_gemm<<<dim3(2, NB), 256, 0, stream>>>(Xt, Wcv, conv_b, XFb);
  // 2) grams: gload_lds staging, packed-bf16 accumulators (no spill at 124-cap)
  gram_acc<128, 256, 2><<<dim3(1, 256), 512, 0, stream>>>(XFb, wq_feat, wk_feat,
                                                          partial_f, 0.0625f);
  gram_acc<256, 128, 4><<<dim3(2, 128), 512, 0, stream>>>(Xtb, wq_time, wk_time,
                                                          partial_t, 0.08838834764831845f);
  // 3) finalize A: merged hierarchical reductions
  reduce_g2<<<384, 256, 0, stream>>>(partial_f, partial_t, l2f, l2t);
  A_fin2<<<80, 256, 0, stream>>>(l2f, l2t, A_feat, A_time, outA_f, outA_t);
  // 4) parallel vector chain + Q-chain + bias fold
  deg_both<<<6, 256, 0, stream>>>(A_feat, A_time, dis_f, dis_t);
  mv_both<<<96, 256, 0, stream>>>(A_feat, A_time, dis_f, dis_t, dis_f, dis_t,
                                  a1f, a1t, w1f, w1t, 0);
  sum_both<<<2, 256, 0, stream>>>(a1f, a1t, sv, 0);
  mv_both<<<96, 256, 0, stream>>>(A_feat, A_time, w1f, w1t, dis_f, dis_t,
                                  a2f, a2t, w2f, w2t, 0);
  sum_both<<<2, 256, 0, stream>>>(a2f, a2t, sv, 1);
  mv_both<<<96, 256, 0, stream>>>(A_feat, A_time, w2f, w2t, dis_f, dis_t,
                                  uf, ut, wdf, wdt, 1);
  qchain<<<dim3(32, 2), 256, 0, stream>>>(gf3_w, gt3_w, proj_w, proj_w + 8192,
                                          S3f, S3t, 128, 128);
  qchain<<<dim3(32, 2), 256, 0, stream>>>(gf2_w, gt2_w, S3f, S3t, S2f, S2t, 128, 128);
  qchain<<<dim3(64, 2), 256, 0, stream>>>(gf1_w, gt1_w, S2f, S2t, Qf, Qt, 256, 128);
  bias_fold<<<2, 128, 0, stream>>>(gf1_b, gf2_w, gf2_b, gf3_w, gf3_b,
                                   gt1_b, gt2_w, gt2_b, gt3_w, gt3_b,
                                   proj_w, sv, cb);
  // 5) per-batch output
  gcn_out<<<NB, 256, 0, stream>>>(XFb, Xtb, uf, ut, Qf, Qt, cb, proj_b, out);
}

// Round 23
// 185.082 us; speedup vs baseline: 1.0407x; 1.0407x over previous
//
#include <hip/hip_runtime.h>
#include <hip/hip_bf16.h>

#define NB 512
#define WD 256
#define NF 128

typedef __attribute__((ext_vector_type(8))) short short8v;
typedef __attribute__((ext_vector_type(4))) float f32x4;

__device__ inline unsigned pk2bf(float a, float b) {
  __hip_bfloat162 h;
  h.x = __float2bfloat16(a);
  h.y = __float2bfloat16(b);
  unsigned r;
  __builtin_memcpy(&r, &h, 4);
  return r;
}

__device__ inline float bf2f(unsigned short u) {
  unsigned v = (unsigned)u << 16;
  float f;
  __builtin_memcpy(&f, &v, 4);
  return f;
}

// ------- prep (merged with wc_cast): X f32 -> flat bf16 + transposed bf16; conv W perm ----
// grid: 16384 tile-blocks (32 per batch) + 192 wc blocks, block-uniform branch.
__global__ __launch_bounds__(256) void prep_wc(
    const float* __restrict__ X, __hip_bfloat16* __restrict__ Xflat,
    __hip_bfloat16* __restrict__ Xt,
    const float* __restrict__ W, __hip_bfloat16* __restrict__ Wc)
{
  __shared__ float tile[32][33];
  int bid = blockIdx.x;
  int t = threadIdx.x;
  if (bid >= 16384) {  // wc_cast part: Wc[o][k*128+i] = bf16(W[o][i][k])
    int idx = (bid - 16384) * 256 + t;
    int o = idx / 384, rem = idx - o * 384;
    int k = rem >> 7, i = rem & 127;
    Wc[idx] = __float2bfloat16(W[(size_t)o * 384 + i * 3 + k]);
    return;
  }
  int b = bid >> 5, tt = bid & 31;
  int i0 = (tt >> 3) * 32, l0 = (tt & 7) * 32;
  const float* Xb = X + (size_t)b * 32768;
  __hip_bfloat16* Fb = Xflat + (size_t)b * 32768;
  __hip_bfloat16* Tb = Xt + (size_t)b * 32768;
  {
    int r = t >> 3, c4 = t & 7;
    float4 v = *(const float4*)(Xb + (size_t)(i0 + r) * 256 + l0 + c4 * 4);
    uint2 p;
    p.x = pk2bf(v.x, v.y);
    p.y = pk2bf(v.z, v.w);
    *(uint2*)(Fb + (size_t)(i0 + r) * 256 + l0 + c4 * 4) = p;
    tile[r][c4 * 4 + 0] = v.x;
    tile[r][c4 * 4 + 1] = v.y;
    tile[r][c4 * 4 + 2] = v.z;
    tile[r][c4 * 4 + 3] = v.w;
  }
  __syncthreads();
  {
    int cr = t >> 3, ch = t & 7;
    float a0 = tile[ch * 4 + 0][cr];
    float a1 = tile[ch * 4 + 1][cr];
    float a2 = tile[ch * 4 + 2][cr];
    float a3 = tile[ch * 4 + 3][cr];
    uint2 q;
    q.x = pk2bf(a0, a1);
    q.y = pk2bf(a2, a3);
    *(uint2*)(Tb + (size_t)(l0 + cr) * 128 + i0 + ch * 4) = q;
  }
}

// ---------------- conv as MFMA GEMM ----------------
__global__ __launch_bounds__(256) void conv_gemm(
    const __hip_bfloat16* __restrict__ Xt, const __hip_bfloat16* __restrict__ Wc,
    const float* __restrict__ bias, __hip_bfloat16* __restrict__ Out)
{
  __shared__ unsigned short ldsA[2][4096];
  __shared__ unsigned short ldsB[2][4096];
  int b = blockIdx.y;
  int trt = blockIdx.x;  // l-tile 0..1
  int t = threadIdx.x, l = t & 63, w = t >> 6;
  int wr = (w >> 1) * 64, wcc = (w & 1) * 64;
  int lr = l & 15, lg = l >> 4;
  const __hip_bfloat16* Ab = Xt + (size_t)b * 32768;
  f32x4 acc[4][4] = {};

#define CSTAGE(buf, ks)                                                               \
  {                                                                                   \
    int kgrp = (ks) >> 2;                                                             \
    int kk = ((ks) & 3) * 32 + lg * 8;                                                \
    _Pragma("unroll") for (int ff = 0; ff < 2; ++ff) {                                \
      int f = 2 * w + ff;                                                             \
      int lrow = trt * 128 + f * 16 + lr + 2 * kgrp - 4;                              \
      uint4 ga = make_uint4(0, 0, 0, 0);                                              \
      if (lrow >= 0) ga = *(const uint4*)(Ab + (size_t)lrow * 128 + kk);              \
      *(uint4*)&ldsA[buf][f * 512 + l * 8] = ga;                                      \
      *(uint4*)&ldsB[buf][f * 512 + l * 8] =                                          \
          *(const uint4*)(Wc + (size_t)(f * 16 + lr) * 384 + (ks) * 32 + lg * 8);     \
    }                                                                                 \
  }

  CSTAGE(0, 0)
  __syncthreads();
  for (int ks = 0; ks < 12; ++ks) {
    int buf = ks & 1;
    if (ks + 1 < 12) CSTAGE((ks + 1) & 1, ks + 1)
    short8v a[4], bq[4];
#pragma unroll
    for (int i = 0; i < 4; ++i)
      a[i] = *(const short8v*)&ldsA[buf][((wr >> 4) + i) * 512 + l * 8];
#pragma unroll
    for (int j = 0; j < 4; ++j)
      bq[j] = *(const short8v*)&ldsB[buf][((wcc >> 4) + j) * 512 + l * 8];
#pragma unroll
    for (int i = 0; i < 4; ++i)
#pragma unroll
      for (int j = 0; j < 4; ++j)
        acc[i][j] = __builtin_amdgcn_mfma_f32_16x16x32_bf16(a[i], bq[j], acc[i][j], 0, 0, 0);
    __syncthreads();
  }

  __hip_bfloat16* Ob = Out + (size_t)b * 32768;
#pragma unroll
  for (int i = 0; i < 4; ++i) {
#pragma unroll
    for (int j = 0; j < 4; ++j) {
      int r = trt * 128 + wr + i * 16 + lg * 4;  // l
      int c = wcc + j * 16 + lr;                 // o
      f32x4 v = acc[i][j];
      float bv = bias[c];
      uint2 p;
      p.x = pk2bf(v[0] + bv, v[1] + bv);
      p.y = pk2bf(v[2] + bv, v[3] + bv);
      *(uint2*)(Ob + (size_t)c * 256 + r) = p;
    }
  }
}

// ------- MFMA gram + softmax + batch-group accumulation (gload_lds staging) -------
// R22 decision: f32 sumA (R21-measured best, 190.7us); packed-bf16 variant was
// a wash on perf and doubled absmax.
template <int N, int D, int BPG>
__global__ __launch_bounds__(512, 1) void gram_acc(
    const __hip_bfloat16* __restrict__ X, const float* __restrict__ Wq,
    const float* __restrict__ Wk, __hip_bfloat16* __restrict__ partial, float scale)
{
  constexpr int NT = N / 16;
  constexpr int KS = D / 32;
  constexpr int C8 = D / 8;
  __shared__ char lds[2][N * D * 2];  // 2 x 64KB
  __shared__ float ldsD[N];
  int t = threadIdx.x, l = t & 63, w = t >> 6;  // 8 waves
  int lr = l & 15, lg = l >> 4;
  int rowbase = blockIdx.x * 128 + w * 16;
  int swz = (lr & 7) << 4;

  if (t < N) ldsD[t] = Wk[(size_t)t * (N + 1)] * scale;
  float dqr[4];
#pragma unroll
  for (int i = 0; i < 4; ++i) dqr[i] = Wq[(size_t)(rowbase + lg * 4 + i) * (N + 1)];

  float sumA[4][NT] = {};

#define GSTAGE(buf, gb)                                                             \
  {                                                                                 \
    const __hip_bfloat16* Xb_ = (gb);                                               \
    _Pragma("unroll") for (int c = 0; c < 8; ++c) {                                 \
      int chunk = c * 512 + t;                                                      \
      int row_ = chunk / C8, j_ = chunk % C8;                                       \
      int gsrc = row_ * D + ((j_ ^ (row_ & 7)) << 3);                               \
      __builtin_amdgcn_global_load_lds(                                             \
          (const __attribute__((address_space(1))) unsigned int*)(const void*)(Xb_ + gsrc), \
          (__attribute__((address_space(3))) unsigned int*)(void*)(&lds[buf][chunk * 16]),  \
          16, 0, 0);                                                                \
    }                                                                               \
  }

  GSTAGE(0, X + (size_t)(blockIdx.y * BPG) * N * D)
  __syncthreads();

#pragma unroll 1
  for (int g = 0; g < BPG; ++g) {
    if (g + 1 < BPG) GSTAGE((g + 1) & 1, X + (size_t)(blockIdx.y * BPG + g + 1) * N * D)
    const char* cur = lds[g & 1];

    f32x4 acc[NT] = {};
#pragma unroll
    for (int ks = 0; ks < KS; ++ks) {
      int coff = (ks * 64 + lg * 16) ^ swz;
      short8v a = *(const short8v*)(cur + (rowbase + lr) * (2 * D) + coff);
#pragma unroll
      for (int m = 0; m < NT; ++m) {
        short8v bb = *(const short8v*)(cur + (m * 16 + lr) * (2 * D) + coff);
        acc[m] = __builtin_amdgcn_mfma_f32_16x16x32_bf16(a, bb, acc[m], 0, 0, 0);
      }
    }

#pragma unroll
    for (int i = 0; i < 4; ++i) {
      float v[NT];
      float mx = -3.0e38f;
#pragma unroll
      for (int m = 0; m < NT; ++m) {
        v[m] = acc[m][i] * dqr[i] * ldsD[m * 16 + lr];
        mx = fmaxf(mx, v[m]);
      }
#pragma unroll
      for (int off = 1; off < 16; off <<= 1) mx = fmaxf(mx, __shfl_xor(mx, off));
      float sum = 0.f;
#pragma unroll
      for (int m = 0; m < NT; ++m) { v[m] = __expf(v[m] - mx); sum += v[m]; }
#pragma unroll
      for (int off = 1; off < 16; off <<= 1) sum += __shfl_xor(sum, off);
      float inv = 1.0f / sum;
#pragma unroll
      for (int m = 0; m < NT; ++m) sumA[i][m] += v[m] * inv;
    }

    if (g + 1 < BPG) __syncthreads();
  }

  __hip_bfloat16* Pp = partial + (size_t)blockIdx.y * N * N;
#pragma unroll
  for (int i = 0; i < 4; ++i) {
    int row = rowbase + lg * 4 + i;
#pragma unroll
    for (int m = 0; m < NT; ++m)
      Pp[(size_t)row * N + m * 16 + lr] = __float2bfloat16(sumA[i][m]);
  }
}

// ------- merged level-1 group reduction (both branches, GS=16) -------
__global__ __launch_bounds__(256) void reduce_g2(
    const __hip_bfloat16* __restrict__ pf, const __hip_bfloat16* __restrict__ pt,
    float* __restrict__ l2f, float* __restrict__ l2t)
{
  int bid = blockIdx.x;
  const __hip_bfloat16* partial;
  float* l2;
  int NN, bx, gy;
  if (bid < 128) { partial = pf; l2 = l2f; NN = 16384; bx = bid & 7; gy = bid >> 3; }
  else { int r2 = bid - 128; partial = pt; l2 = l2t; NN = 65536; bx = r2 & 31; gy = r2 >> 5; }
  int idx = (bx * 256 + threadIdx.x) * 8;
  const __hip_bfloat16* p = partial + (size_t)gy * 16 * NN + idx;
  float a[8] = {};
#pragma unroll 4
  for (int g = 0; g < 16; ++g) {
    uint4 u = *(const uint4*)(p + (size_t)g * NN);
    unsigned arr[4] = {u.x, u.y, u.z, u.w};
#pragma unroll
    for (int q = 0; q < 4; ++q) {
      a[2 * q] += bf2f((unsigned short)(arr[q] & 0xffff));
      a[2 * q + 1] += bf2f((unsigned short)(arr[q] >> 16));
    }
  }
  float* dst = l2 + (size_t)gy * NN + idx;
  *(float4*)dst = make_float4(a[0], a[1], a[2], a[3]);
  *(float4*)(dst + 4) = make_float4(a[4], a[5], a[6], a[7]);
}

// ------- merged final mean (both branches): A = (1/512) sum_g l2[g] -------
__global__ __launch_bounds__(256) void A_fin2(
    const float* __restrict__ l2f, const float* __restrict__ l2t,
    float* __restrict__ A1f, float* __restrict__ A1t,
    float* __restrict__ A2f, float* __restrict__ A2t)
{
  int bid = blockIdx.x;
  const float* src;
  float *A1, *A2;
  int NN, G, ib;
  if (bid < 16) { src = l2f; A1 = A1f; A2 = A2f; NN = 16384; G = 16; ib = bid; }
  else { src = l2t; A1 = A1t; A2 = A2t; NN = 65536; G = 8; ib = bid - 16; }
  int idx = (ib * 256 + threadIdx.x) * 4;
  float4 a = make_float4(0.f, 0.f, 0.f, 0.f);
  for (int g = 0; g < G; ++g) {
    float4 v = *(const float4*)(src + (size_t)g * NN + idx);
    a.x += v.x; a.y += v.y; a.z += v.z; a.w += v.w;
  }
  a.x *= (1.0f / NB); a.y *= (1.0f / NB); a.z *= (1.0f / NB); a.w *= (1.0f / NB);
  *(float4*)(A1 + idx) = a;
  *(float4*)(A2 + idx) = a;
}

// ------- dis for both branches -------
__global__ __launch_bounds__(256) void deg_both(
    const float* __restrict__ Af, const float* __restrict__ At,
    float* __restrict__ disf, float* __restrict__ dist)
{
  __shared__ float red[4][64];
  int bid = blockIdx.x;  // 0..1 feat, 2..5 time
  int branch = bid >= 2;
  int N = branch ? 256 : 128;
  const float* A = branch ? At : Af;
  float* dis = branch ? dist : disf;
  int cb = (branch ? (bid - 2) : bid) * 64;
  int t = threadIdx.x, lane = t & 63, rg = t >> 6;
  float s = 0.f;
  for (int r = rg; r < N; r += 4) s += A[(size_t)r * N + cb + lane];
  red[rg][lane] = s;
  __syncthreads();
  if (t < 64) {
    float d = red[0][t] + red[1][t] + red[2][t] + red[3][t];
    dis[cb + t] = (d > 0.f) ? (1.0f / sqrtf(d)) : 0.0f;
  }
}

// ------- one matvec stage (both branches): a[r] = dis[r]*sum_c A[r,c] v[c] -------
__global__ __launch_bounds__(256) void mv_both(
    const float* __restrict__ Af, const float* __restrict__ At,
    const float* __restrict__ vf, const float* __restrict__ vt,
    const float* __restrict__ disf, const float* __restrict__ dist,
    float* __restrict__ aof, float* __restrict__ aot,
    float* __restrict__ wof, float* __restrict__ wot, int doScale)
{
  int bid = blockIdx.x;  // 0..31 feat (128 rows), 32..95 time (256 rows)
  int branch = bid >= 32;
  int N = branch ? 256 : 128;
  const float* A = branch ? At : Af;
  const float* v = branch ? vt : vf;
  const float* dis = branch ? dist : disf;
  float* ao = branch ? aot : aof;
  float* wo = branch ? wot : wof;
  int r = (branch ? (bid - 32) : bid) * 4 + (threadIdx.x >> 6);
  int lane = threadIdx.x & 63;
  const float* Ar = A + (size_t)r * N;
  float s = 0.f;
  for (int c = lane * 4; c < N; c += 256) {
    float4 av = *(const float4*)(Ar + c);
    s += av.x * v[c] + av.y * v[c + 1] + av.z * v[c + 2] + av.w * v[c + 3];
  }
#pragma unroll
  for (int off = 32; off > 0; off >>= 1) s += __shfl_xor(s, off);
  if (lane == 0) {
    float a = dis[r] * s;
    float scale = doScale ? (branch ? (1.0f / 256.0f) : (1.0f / 128.0f)) : 1.0f;
    ao[r] = a * scale;
    wo[r] = dis[r] * a;
  }
}

// ------- parallel Q-chain stage: C[M][64] = A[M][128] * B[128][64] -------
__global__ __launch_bounds__(256) void qchain(
    const float* __restrict__ Af, const float* __restrict__ At,
    const float* __restrict__ Bf, const float* __restrict__ Bt,
    float* __restrict__ Cf, float* __restrict__ Ct, int Mf, int Mt)
{
  int branch = blockIdx.y;
  const float* A = branch ? At : Af;
  const float* B = branch ? Bt : Bf;
  float* C = branch ? Ct : Cf;
  int M = branch ? Mt : Mf;
  int r = blockIdx.x * 4 + (threadIdx.x >> 6);
  int o = threadIdx.x & 63;
  if (r >= M) return;
  const float* Ar = A + (size_t)r * 128;
  float s = 0.f;
#pragma unroll 8
  for (int k = 0; k < 128; k += 4) {
    float4 wv = *(const float4*)(Ar + k);
    s += wv.x * B[k * 64 + o] + wv.y * B[(k + 1) * 64 + o] +
         wv.z * B[(k + 2) * 64 + o] + wv.w * B[(k + 3) * 64 + o];
  }
  C[(size_t)r * 64 + o] = s;
}

// ------- bias fold (now also computes s1,s2 from a1,a2 — sum_both removed) -------
__global__ __launch_bounds__(128) void bias_fold(
    const float* __restrict__ gf1b, const float* __restrict__ gf2w, const float* __restrict__ gf2b,
    const float* __restrict__ gf3w, const float* __restrict__ gf3b,
    const float* __restrict__ gt1b, const float* __restrict__ gt2w, const float* __restrict__ gt2b,
    const float* __restrict__ gt3w, const float* __restrict__ gt3b,
    const float* __restrict__ projw,
    const float* __restrict__ a1f, const float* __restrict__ a1t,
    const float* __restrict__ a2f, const float* __restrict__ a2t,
    float* __restrict__ cb)
{
  int branch = blockIdx.x;
  int N = branch ? 256 : 128;
  const float* W2 = branch ? gt2w : gf2w;
  const float* W3 = branch ? gt3w : gf3w;
  const float* b1 = branch ? gt1b : gf1b;
  const float* b2 = branch ? gt2b : gf2b;
  const float* b3 = branch ? gt3b : gf3b;
  const float* a1 = branch ? a1t : a1f;
  const float* a2 = branch ? a2t : a2f;
  const float* P = projw + (size_t)branch * 128 * 64;
  __shared__ float r1[128], cf[128], redsum[4];
  int t = threadIdx.x, lane = t & 63, wv = t >> 6;

  // s1 = sum(a1), s2 = sum(a2) -- 128 threads, deterministic tree
  {
    float x1 = 0.f, x2 = 0.f;
    for (int i = t; i < N; i += 128) { x1 += a1[i]; x2 += a2[i]; }
#pragma unroll
    for (int off = 32; off > 0; off >>= 1) {
      x1 += __shfl_xor(x1, off);
      x2 += __shfl_xor(x2, off);
    }
    if (lane == 0) { redsum[wv * 2] = x1; redsum[wv * 2 + 1] = x2; }
  }
  __syncthreads();
  float s1 = redsum[0] + redsum[2];
  float s2 = redsum[1] + redsum[3];

  {
    float s = 0.f;
#pragma unroll 4
    for (int h = 0; h < 128; ++h) s += b1[h] * W2[(size_t)h * 128 + t];
    r1[t] = s;
  }
  __syncthreads();
  {
    float sa = 0.f, sb = 0.f;
#pragma unroll 4
    for (int h = 0; h < 128; ++h) {
      float w3v = W3[(size_t)h * 128 + t];
      sa += r1[h] * w3v;
      sb += b2[h] * w3v;
    }
    cf[t] = (s2 * sa + s1 * sb) * (1.0f / N) + b3[t];
  }
  __syncthreads();
  if (t < 64) {
    float s = 0.f;
#pragma unroll 4
    for (int h = 0; h < 128; ++h) s += cf[h] * P[(size_t)h * 64 + t];
    cb[branch * 64 + t] = s;
  }
}

// ------- final: out[b] = (uf'XF[b])Qf + (ut'Xt[b])Qt + pb + cb_f + cb_t -------
__global__ __launch_bounds__(256) void gcn_out(
    const __hip_bfloat16* __restrict__ XF, const __hip_bfloat16* __restrict__ Xt,
    const float* __restrict__ uf, const float* __restrict__ ut,
    const float* __restrict__ Qf, const float* __restrict__ Qt,
    const float* __restrict__ cb, const float* __restrict__ pb,
    float* __restrict__ out)
{
  __shared__ float red[2048];
  __shared__ float yfL[256], ytL[128], red3[4][64];
  int b = blockIdx.x, t = threadIdx.x;

  {
    int rr = t >> 5, cc = t & 31;
    const __hip_bfloat16* base = XF + (size_t)b * 32768;
    float acc[8] = {};
    for (int it = 0; it < 16; ++it) {
      int row = it * 8 + rr;
      float uw = uf[row];
      uint4 v = *(const uint4*)(base + (size_t)row * 256 + cc * 8);
      unsigned arr[4] = {v.x, v.y, v.z, v.w};
#pragma unroll
      for (int q = 0; q < 4; ++q) {
        acc[2 * q] += uw * bf2f((unsigned short)(arr[q] & 0xffff));
        acc[2 * q + 1] += uw * bf2f((unsigned short)(arr[q] >> 16));
      }
    }
#pragma unroll
    for (int j = 0; j < 8; ++j) red[rr * 256 + cc * 8 + j] = acc[j];
  }
  __syncthreads();
  {
    float s = 0.f;
#pragma unroll
    for (int g = 0; g < 8; ++g) s += red[g * 256 + t];
    yfL[t] = s;
  }
  __syncthreads();
  {
    int rr = t >> 4, cc = t & 15;
    const __hip_bfloat16* base = Xt + (size_t)b * 32768;
    float acc[8] = {};
    for (int it = 0; it < 16; ++it) {
      int row = it * 16 + rr;
      float uw = ut[row];
      uint4 v = *(const uint4*)(base + (size_t)row * 128 + cc * 8);
      unsigned arr[4] = {v.x, v.y, v.z, v.w};
#pragma unroll
      for (int q = 0; q < 4; ++q) {
        acc[2 * q] += uw * bf2f((unsigned short)(arr[q] & 0xffff));
        acc[2 * q + 1] += uw * bf2f((unsigned short)(arr[q] >> 16));
      }
    }
#pragma unroll
    for (int j = 0; j < 8; ++j) red[rr * 128 + cc * 8 + j] = acc[j];
  }
  __syncthreads();
  if (t < 128) {
    float s = 0.f;
#pragma unroll
    for (int g = 0; g < 16; ++g) s += red[g * 128 + t];
    ytL[t] = s;
  }
  __syncthreads();
  {
    int grp = t >> 6, o = t & 63;
    float s = 0.f;
    for (int jj = 0; jj < 64; ++jj) {
      int j = grp * 64 + jj;
      s += yfL[j] * Qf[(size_t)j * 64 + o];
    }
    for (int jj = 0; jj < 32; ++jj) {
      int j = grp * 32 + jj;
      s += ytL[j] * Qt[(size_t)j * 64 + o];
    }
    red3[grp][o] = s;
  }
  __syncthreads();
  if (t < 64) {
    out[(size_t)b * 64 + t] = red3[0][t] + red3[1][t] + red3[2][t] + red3[3][t] +
                              pb[t] + cb[t] + cb[64 + t];
  }
}

extern "C" void kernel_launch(void* const* d_in, const int* in_sizes, int n_in,
                              void* d_out, int out_size, void* d_ws, size_t ws_size,
                              hipStream_t stream)
{
  const float* X_time = (const float*)d_in[0];
  const float* conv_w = (const float*)d_in[1];
  const float* conv_b = (const float*)d_in[2];
  const float* wq_feat = (const float*)d_in[3];
  const float* wk_feat = (const float*)d_in[4];
  const float* wq_time = (const float*)d_in[5];
  const float* wk_time = (const float*)d_in[6];
  const float* gf1_w = (const float*)d_in[7];
  const float* gf1_b = (const float*)d_in[8];
  const float* gf2_w = (const float*)d_in[9];
  const float* gf2_b = (const float*)d_in[10];
  const float* gf3_w = (const float*)d_in[11];
  const float* gf3_b = (const float*)d_in[12];
  const float* gt1_w = (const float*)d_in[13];
  const float* gt1_b = (const float*)d_in[14];
  const float* gt2_w = (const float*)d_in[15];
  const float* gt2_b = (const float*)d_in[16];
  const float* gt3_w = (const float*)d_in[17];
  const float* gt3_b = (const float*)d_in[18];
  const float* proj_w = (const float*)d_in[19];
  const float* proj_b = (const float*)d_in[20];

  typedef __hip_bfloat16 bf16;
  char* ws = (char*)d_ws;
  const size_t MiB = 1ull << 20;
  bf16* XFb = (bf16*)ws;                         // 32MB
  bf16* Xtb = (bf16*)(ws + 34 * MiB);            // 32MB
  bf16* partial_f = (bf16*)(ws + 68 * MiB);      // 8MB
  bf16* partial_t = (bf16*)(ws + 100 * MiB);     // 16MB
  bf16* Xt = (bf16*)(ws + 100 * MiB);            // 32MB, conv-only
  float* l2f = (float*)(ws + 164 * MiB);         // 1MB
  float* l2t = (float*)(ws + 166 * MiB);         // 2MB
  char* SM = ws + 171 * MiB;
  float* A_feat = (float*)SM;                    // 64KB
  float* A_time = (float*)(SM + 65536);          // 256KB
  float* uf = (float*)(SM + 327680);
  float* ut = (float*)(SM + 328704);
  float* Qf = (float*)(SM + 331776);
  float* Qt = (float*)(SM + 397312);
  float* cb = (float*)(SM + 430080);
  bf16* Wcv = (bf16*)(SM + 432128);
  float* S3f = (float*)(SM + 530432);
  float* S3t = (float*)(SM + 563200);
  float* S2f = (float*)(SM + 595968);
  float* S2t = (float*)(SM + 628736);
  float* dis_f = (float*)(SM + 661504);
  float* dis_t = (float*)(SM + 662528);
  float* a1f = (float*)(SM + 663552);
  float* a1t = (float*)(SM + 664576);
  float* a2f = (float*)(SM + 665600);
  float* a2t = (float*)(SM + 666624);
  float* w1f = (float*)(SM + 667648);
  float* w1t = (float*)(SM + 668672);
  float* w2f = (float*)(SM + 669696);
  float* w2t = (float*)(SM + 670720);
  float* wdf = (float*)(SM + 671744);
  float* wdt = (float*)(SM + 672768);

  float* out = (float*)d_out;
  float* outA_f = out + 32768;
  float* outA_t = out + 49152;

  // 1) prep (merged wc_cast) + conv
  prep_wc<<<16384 + 192, 256, 0, stream>>>(X_time, Xtb, Xt, conv_w, Wcv);
  conv_gemm<<<dim3(2, NB), 256, 0, stream>>>(Xt, Wcv, conv_b, XFb);
  // 2) grams: gload_lds double-buffered staging, bf16 partials (R21 config)
  gram_acc<128, 256, 2><<<dim3(1, 256), 512, 0, stream>>>(XFb, wq_feat, wk_feat,
                                                          partial_f, 0.0625f);
  gram_acc<256, 128, 4><<<dim3(2, 128), 512, 0, stream>>>(Xtb, wq_time, wk_time,
                                                          partial_t, 0.08838834764831845f);
  // 3) finalize A: merged hierarchical reductions
  reduce_g2<<<384, 256, 0, stream>>>(partial_f, partial_t, l2f, l2t);
  A_fin2<<<80, 256, 0, stream>>>(l2f, l2t, A_feat, A_time, outA_f, outA_t);
  // 4) parallel vector chain (sums folded into bias_fold) + Q-chain
  deg_both<<<6, 256, 0, stream>>>(A_feat, A_time, dis_f, dis_t);
  mv_both<<<96, 256, 0, stream>>>(A_feat, A_time, dis_f, dis_t, dis_f, dis_t,
                                  a1f, a1t, w1f, w1t, 0);
  mv_both<<<96, 256, 0, stream>>>(A_feat, A_time, w1f, w1t, dis_f, dis_t,
                                  a2f, a2t, w2f, w2t, 0);
  mv_both<<<96, 256, 0, stream>>>(A_feat, A_time, w2f, w2t, dis_f, dis_t,
                                  uf, ut, wdf, wdt, 1);
  qchain<<<dim3(32, 2), 256, 0, stream>>>(gf3_w, gt3_w, proj_w, proj_w + 8192,
                                          S3f, S3t, 128, 128);
  qchain<<<dim3(32, 2), 256, 0, stream>>>(gf2_w, gt2_w, S3f, S3t, S2f, S2t, 128, 128);
  qchain<<<dim3(64, 2), 256, 0, stream>>>(gf1_w, gt1_w, S2f, S2t, Qf, Qt, 256, 128);
  bias_fold<<<2, 128, 0, stream>>>(gf1_b, gf2_w, gf2_b, gf3_w, gf3_b,
                                   gt1_b, gt2_w, gt2_b, gt3_w, gt3_b,
                                   proj_w, a1f, a1t, a2f, a2t, cb);
  // 5) per-batch output
  gcn_out<<<NB, 256, 0, stream>>>(XFb, Xtb, uf, ut, Qf, Qt, cb, proj_b, out);
}

// Round 24
// 181.372 us; speedup vs baseline: 1.0620x; 1.0205x over previous
//
#include <hip/hip_runtime.h>
#include <hip/hip_bf16.h>

#define NB 512
#define WD 256
#define NF 128

typedef __attribute__((ext_vector_type(8))) short short8v;
typedef __attribute__((ext_vector_type(4))) float f32x4;

__device__ inline unsigned pk2bf(float a, float b) {
  __hip_bfloat162 h;
  h.x = __float2bfloat16(a);
  h.y = __float2bfloat16(b);
  unsigned r;
  __builtin_memcpy(&r, &h, 4);
  return r;
}

__device__ inline float bf2f(unsigned short u) {
  unsigned v = (unsigned)u << 16;
  float f;
  __builtin_memcpy(&f, &v, 4);
  return f;
}

// ------- prep (merged with wc_cast): X f32 -> flat bf16 + transposed bf16; conv W perm ----
__global__ __launch_bounds__(256) void prep_wc(
    const float* __restrict__ X, __hip_bfloat16* __restrict__ Xflat,
    __hip_bfloat16* __restrict__ Xt,
    const float* __restrict__ W, __hip_bfloat16* __restrict__ Wc)
{
  __shared__ float tile[32][33];
  int bid = blockIdx.x;
  int t = threadIdx.x;
  if (bid >= 16384) {  // wc_cast part: Wc[o][k*128+i] = bf16(W[o][i][k])
    int idx = (bid - 16384) * 256 + t;
    int o = idx / 384, rem = idx - o * 384;
    int k = rem >> 7, i = rem & 127;
    Wc[idx] = __float2bfloat16(W[(size_t)o * 384 + i * 3 + k]);
    return;
  }
  int b = bid >> 5, tt = bid & 31;
  int i0 = (tt >> 3) * 32, l0 = (tt & 7) * 32;
  const float* Xb = X + (size_t)b * 32768;
  __hip_bfloat16* Fb = Xflat + (size_t)b * 32768;
  __hip_bfloat16* Tb = Xt + (size_t)b * 32768;
  {
    int r = t >> 3, c4 = t & 7;
    float4 v = *(const float4*)(Xb + (size_t)(i0 + r) * 256 + l0 + c4 * 4);
    uint2 p;
    p.x = pk2bf(v.x, v.y);
    p.y = pk2bf(v.z, v.w);
    *(uint2*)(Fb + (size_t)(i0 + r) * 256 + l0 + c4 * 4) = p;
    tile[r][c4 * 4 + 0] = v.x;
    tile[r][c4 * 4 + 1] = v.y;
    tile[r][c4 * 4 + 2] = v.z;
    tile[r][c4 * 4 + 3] = v.w;
  }
  __syncthreads();
  {
    int cr = t >> 3, ch = t & 7;
    float a0 = tile[ch * 4 + 0][cr];
    float a1 = tile[ch * 4 + 1][cr];
    float a2 = tile[ch * 4 + 2][cr];
    float a3 = tile[ch * 4 + 3][cr];
    uint2 q;
    q.x = pk2bf(a0, a1);
    q.y = pk2bf(a2, a3);
    *(uint2*)(Tb + (size_t)(l0 + cr) * 128 + i0 + ch * 4) = q;
  }
}

// ---------------- conv as MFMA GEMM ----------------
__global__ __launch_bounds__(256) void conv_gemm(
    const __hip_bfloat16* __restrict__ Xt, const __hip_bfloat16* __restrict__ Wc,
    const float* __restrict__ bias, __hip_bfloat16* __restrict__ Out)
{
  __shared__ unsigned short ldsA[2][4096];
  __shared__ unsigned short ldsB[2][4096];
  int b = blockIdx.y;
  int trt = blockIdx.x;  // l-tile 0..1
  int t = threadIdx.x, l = t & 63, w = t >> 6;
  int wr = (w >> 1) * 64, wcc = (w & 1) * 64;
  int lr = l & 15, lg = l >> 4;
  const __hip_bfloat16* Ab = Xt + (size_t)b * 32768;
  f32x4 acc[4][4] = {};

#define CSTAGE(buf, ks)                                                               \
  {                                                                                   \
    int kgrp = (ks) >> 2;                                                             \
    int kk = ((ks) & 3) * 32 + lg * 8;                                                \
    _Pragma("unroll") for (int ff = 0; ff < 2; ++ff) {                                \
      int f = 2 * w + ff;                                                             \
      int lrow = trt * 128 + f * 16 + lr + 2 * kgrp - 4;                              \
      uint4 ga = make_uint4(0, 0, 0, 0);                                              \
      if (lrow >= 0) ga = *(const uint4*)(Ab + (size_t)lrow * 128 + kk);              \
      *(uint4*)&ldsA[buf][f * 512 + l * 8] = ga;                                      \
      *(uint4*)&ldsB[buf][f * 512 + l * 8] =                                          \
          *(const uint4*)(Wc + (size_t)(f * 16 + lr) * 384 + (ks) * 32 + lg * 8);     \
    }                                                                                 \
  }

  CSTAGE(0, 0)
  __syncthreads();
  for (int ks = 0; ks < 12; ++ks) {
    int buf = ks & 1;
    if (ks + 1 < 12) CSTAGE((ks + 1) & 1, ks + 1)
    short8v a[4], bq[4];
#pragma unroll
    for (int i = 0; i < 4; ++i)
      a[i] = *(const short8v*)&ldsA[buf][((wr >> 4) + i) * 512 + l * 8];
#pragma unroll
    for (int j = 0; j < 4; ++j)
      bq[j] = *(const short8v*)&ldsB[buf][((wcc >> 4) + j) * 512 + l * 8];
#pragma unroll
    for (int i = 0; i < 4; ++i)
#pragma unroll
      for (int j = 0; j < 4; ++j)
        acc[i][j] = __builtin_amdgcn_mfma_f32_16x16x32_bf16(a[i], bq[j], acc[i][j], 0, 0, 0);
    __syncthreads();
  }

  __hip_bfloat16* Ob = Out + (size_t)b * 32768;
#pragma unroll
  for (int i = 0; i < 4; ++i) {
#pragma unroll
    for (int j = 0; j < 4; ++j) {
      int r = trt * 128 + wr + i * 16 + lg * 4;  // l
      int c = wcc + j * 16 + lr;                 // o
      f32x4 v = acc[i][j];
      float bv = bias[c];
      uint2 p;
      p.x = pk2bf(v[0] + bv, v[1] + bv);
      p.y = pk2bf(v[2] + bv, v[3] + bv);
      *(uint2*)(Ob + (size_t)c * 256 + r) = p;
    }
  }
}

// ------- MFMA gram body (device fn; shared by both branches of gram_both) -------
template <int N, int D, int BPG>
__device__ __forceinline__ void gram_body(
    int bx, int by,
    const __hip_bfloat16* __restrict__ X, const float* __restrict__ Wq,
    const float* __restrict__ Wk, __hip_bfloat16* __restrict__ partial, float scale,
    char* lds0, char* lds1, float* ldsD)
{
  constexpr int NT = N / 16;
  constexpr int KS = D / 32;
  constexpr int C8 = D / 8;
  int t = threadIdx.x, l = t & 63, w = t >> 6;  // 8 waves
  int lr = l & 15, lg = l >> 4;
  int rowbase = bx * 128 + w * 16;
  int swz = (lr & 7) << 4;

  if (t < N) ldsD[t] = Wk[(size_t)t * (N + 1)] * scale;
  float dqr[4];
#pragma unroll
  for (int i = 0; i < 4; ++i) dqr[i] = Wq[(size_t)(rowbase + lg * 4 + i) * (N + 1)];

  float sumA[4][NT] = {};

#define GSTAGE(bufp, gb)                                                            \
  {                                                                                 \
    const __hip_bfloat16* Xb_ = (gb);                                               \
    _Pragma("unroll") for (int c = 0; c < 8; ++c) {                                 \
      int chunk = c * 512 + t;                                                      \
      int row_ = chunk / C8, j_ = chunk % C8;                                       \
      int gsrc = row_ * D + ((j_ ^ (row_ & 7)) << 3);                               \
      __builtin_amdgcn_global_load_lds(                                             \
          (const __attribute__((address_space(1))) unsigned int*)(const void*)(Xb_ + gsrc), \
          (__attribute__((address_space(3))) unsigned int*)(void*)((bufp) + chunk * 16),    \
          16, 0, 0);                                                                \
    }                                                                               \
  }

  GSTAGE(lds0, X + (size_t)(by * BPG) * N * D)
  __syncthreads();

#pragma unroll 1
  for (int g = 0; g < BPG; ++g) {
    if (g + 1 < BPG)
      GSTAGE(((g + 1) & 1) ? lds1 : lds0, X + (size_t)(by * BPG + g + 1) * N * D)
    const char* cur = (g & 1) ? lds1 : lds0;

    f32x4 acc[NT] = {};
#pragma unroll
    for (int ks = 0; ks < KS; ++ks) {
      int coff = (ks * 64 + lg * 16) ^ swz;
      short8v a = *(const short8v*)(cur + (rowbase + lr) * (2 * D) + coff);
#pragma unroll
      for (int m = 0; m < NT; ++m) {
        short8v bb = *(const short8v*)(cur + (m * 16 + lr) * (2 * D) + coff);
        acc[m] = __builtin_amdgcn_mfma_f32_16x16x32_bf16(a, bb, acc[m], 0, 0, 0);
      }
    }

#pragma unroll
    for (int i = 0; i < 4; ++i) {
      float v[NT];
      float mx = -3.0e38f;
#pragma unroll
      for (int m = 0; m < NT; ++m) {
        v[m] = acc[m][i] * dqr[i] * ldsD[m * 16 + lr];
        mx = fmaxf(mx, v[m]);
      }
#pragma unroll
      for (int off = 1; off < 16; off <<= 1) mx = fmaxf(mx, __shfl_xor(mx, off));
      float sum = 0.f;
#pragma unroll
      for (int m = 0; m < NT; ++m) { v[m] = __expf(v[m] - mx); sum += v[m]; }
#pragma unroll
      for (int off = 1; off < 16; off <<= 1) sum += __shfl_xor(sum, off);
      float inv = 1.0f / sum;
#pragma unroll
      for (int m = 0; m < NT; ++m) sumA[i][m] += v[m] * inv;
    }

    if (g + 1 < BPG) __syncthreads();
  }

  __hip_bfloat16* Pp = partial + (size_t)by * N * N;
#pragma unroll
  for (int i = 0; i < 4; ++i) {
    int row = rowbase + lg * 4 + i;
#pragma unroll
    for (int m = 0; m < NT; ++m)
      Pp[(size_t)row * N + m * 16 + lr] = __float2bfloat16(sumA[i][m]);
  }
}

// ------- merged gram dispatch: blocks 0..255 feat, 256..511 time (tail-packing) -------
__global__ __launch_bounds__(512, 1) void gram_both(
    const __hip_bfloat16* __restrict__ XFb, const float* __restrict__ wqf,
    const float* __restrict__ wkf, __hip_bfloat16* __restrict__ pf,
    const __hip_bfloat16* __restrict__ Xtb, const float* __restrict__ wqt,
    const float* __restrict__ wkt, __hip_bfloat16* __restrict__ pt)
{
  __shared__ char lds0[65536], lds1[65536];
  __shared__ float ldsD[256];
  int bid = blockIdx.x;
  if (bid < 256) {
    gram_body<128, 256, 2>(0, bid, XFb, wqf, wkf, pf, 0.0625f, lds0, lds1, ldsD);
  } else {
    int r = bid - 256;
    gram_body<256, 128, 4>(r & 1, r >> 1, Xtb, wqt, wkt, pt, 0.08838834764831845f,
                           lds0, lds1, ldsD);
  }
}

// ------- merged level-1 group reduction (both branches, GS=16) -------
__global__ __launch_bounds__(256) void reduce_g2(
    const __hip_bfloat16* __restrict__ pf, const __hip_bfloat16* __restrict__ pt,
    float* __restrict__ l2f, float* __restrict__ l2t)
{
  int bid = blockIdx.x;
  const __hip_bfloat16* partial;
  float* l2;
  int NN, bx, gy;
  if (bid < 128) { partial = pf; l2 = l2f; NN = 16384; bx = bid & 7; gy = bid >> 3; }
  else { int r2 = bid - 128; partial = pt; l2 = l2t; NN = 65536; bx = r2 & 31; gy = r2 >> 5; }
  int idx = (bx * 256 + threadIdx.x) * 8;
  const __hip_bfloat16* p = partial + (size_t)gy * 16 * NN + idx;
  float a[8] = {};
#pragma unroll 4
  for (int g = 0; g < 16; ++g) {
    uint4 u = *(const uint4*)(p + (size_t)g * NN);
    unsigned arr[4] = {u.x, u.y, u.z, u.w};
#pragma unroll
    for (int q = 0; q < 4; ++q) {
      a[2 * q] += bf2f((unsigned short)(arr[q] & 0xffff));
      a[2 * q + 1] += bf2f((unsigned short)(arr[q] >> 16));
    }
  }
  float* dst = l2 + (size_t)gy * NN + idx;
  *(float4*)dst = make_float4(a[0], a[1], a[2], a[3]);
  *(float4*)(dst + 4) = make_float4(a[4], a[5], a[6], a[7]);
}

// ------- merged final mean (both branches): A = (1/512) sum_g l2[g] -------
__global__ __launch_bounds__(256) void A_fin2(
    const float* __restrict__ l2f, const float* __restrict__ l2t,
    float* __restrict__ A1f, float* __restrict__ A1t,
    float* __restrict__ A2f, float* __restrict__ A2t)
{
  int bid = blockIdx.x;
  const float* src;
  float *A1, *A2;
  int NN, G, ib;
  if (bid < 16) { src = l2f; A1 = A1f; A2 = A2f; NN = 16384; G = 16; ib = bid; }
  else { src = l2t; A1 = A1t; A2 = A2t; NN = 65536; G = 8; ib = bid - 16; }
  int idx = (ib * 256 + threadIdx.x) * 4;
  float4 a = make_float4(0.f, 0.f, 0.f, 0.f);
  for (int g = 0; g < G; ++g) {
    float4 v = *(const float4*)(src + (size_t)g * NN + idx);
    a.x += v.x; a.y += v.y; a.z += v.z; a.w += v.w;
  }
  a.x *= (1.0f / NB); a.y *= (1.0f / NB); a.z *= (1.0f / NB); a.w *= (1.0f / NB);
  *(float4*)(A1 + idx) = a;
  *(float4*)(A2 + idx) = a;
}

// ------- dis for both branches -------
__global__ __launch_bounds__(256) void deg_both(
    const float* __restrict__ Af, const float* __restrict__ At,
    float* __restrict__ disf, float* __restrict__ dist)
{
  __shared__ float red[4][64];
  int bid = blockIdx.x;  // 0..1 feat, 2..5 time
  int branch = bid >= 2;
  int N = branch ? 256 : 128;
  const float* A = branch ? At : Af;
  float* dis = branch ? dist : disf;
  int cb = (branch ? (bid - 2) : bid) * 64;
  int t = threadIdx.x, lane = t & 63, rg = t >> 6;
  float s = 0.f;
  for (int r = rg; r < N; r += 4) s += A[(size_t)r * N + cb + lane];
  red[rg][lane] = s;
  __syncthreads();
  if (t < 64) {
    float d = red[0][t] + red[1][t] + red[2][t] + red[3][t];
    dis[cb + t] = (d > 0.f) ? (1.0f / sqrtf(d)) : 0.0f;
  }
}

// ------- one matvec stage (both branches): a[r] = dis[r]*sum_c A[r,c] v[c] -------
__global__ __launch_bounds__(256) void mv_both(
    const float* __restrict__ Af, const float* __restrict__ At,
    const float* __restrict__ vf, const float* __restrict__ vt,
    const float* __restrict__ disf, const float* __restrict__ dist,
    float* __restrict__ aof, float* __restrict__ aot,
    float* __restrict__ wof, float* __restrict__ wot, int doScale)
{
  int bid = blockIdx.x;  // 0..31 feat (128 rows), 32..95 time (256 rows)
  int branch = bid >= 32;
  int N = branch ? 256 : 128;
  const float* A = branch ? At : Af;
  const float* v = branch ? vt : vf;
  const float* dis = branch ? dist : disf;
  float* ao = branch ? aot : aof;
  float* wo = branch ? wot : wof;
  int r = (branch ? (bid - 32) : bid) * 4 + (threadIdx.x >> 6);
  int lane = threadIdx.x & 63;
  const float* Ar = A + (size_t)r * N;
  float s = 0.f;
  for (int c = lane * 4; c < N; c += 256) {
    float4 av = *(const float4*)(Ar + c);
    s += av.x * v[c] + av.y * v[c + 1] + av.z * v[c + 2] + av.w * v[c + 3];
  }
#pragma unroll
  for (int off = 32; off > 0; off >>= 1) s += __shfl_xor(s, off);
  if (lane == 0) {
    float a = dis[r] * s;
    float scale = doScale ? (branch ? (1.0f / 256.0f) : (1.0f / 128.0f)) : 1.0f;
    ao[r] = a * scale;
    wo[r] = dis[r] * a;
  }
}

// ------- parallel Q-chain stage: C[M][64] = A[M][128] * B[128][64] -------
__global__ __launch_bounds__(256) void qchain(
    const float* __restrict__ Af, const float* __restrict__ At,
    const float* __restrict__ Bf, const float* __restrict__ Bt,
    float* __restrict__ Cf, float* __restrict__ Ct, int Mf, int Mt)
{
  int branch = blockIdx.y;
  const float* A = branch ? At : Af;
  const float* B = branch ? Bt : Bf;
  float* C = branch ? Ct : Cf;
  int M = branch ? Mt : Mf;
  int r = blockIdx.x * 4 + (threadIdx.x >> 6);
  int o = threadIdx.x & 63;
  if (r >= M) return;
  const float* Ar = A + (size_t)r * 128;
  float s = 0.f;
#pragma unroll 8
  for (int k = 0; k < 128; k += 4) {
    float4 wv = *(const float4*)(Ar + k);
    s += wv.x * B[k * 64 + o] + wv.y * B[(k + 1) * 64 + o] +
         wv.z * B[(k + 2) * 64 + o] + wv.w * B[(k + 3) * 64 + o];
  }
  C[(size_t)r * 64 + o] = s;
}

// ------- bias fold (computes s1,s2 from a1,a2 in-kernel) -------
__global__ __launch_bounds__(128) void bias_fold(
    const float* __restrict__ gf1b, const float* __restrict__ gf2w, const float* __restrict__ gf2b,
    const float* __restrict__ gf3w, const float* __restrict__ gf3b,
    const float* __restrict__ gt1b, const float* __restrict__ gt2w, const float* __restrict__ gt2b,
    const float* __restrict__ gt3w, const float* __restrict__ gt3b,
    const float* __restrict__ projw,
    const float* __restrict__ a1f, const float* __restrict__ a1t,
    const float* __restrict__ a2f, const float* __restrict__ a2t,
    float* __restrict__ cb)
{
  int branch = blockIdx.x;
  int N = branch ? 256 : 128;
  const float* W2 = branch ? gt2w : gf2w;
  const float* W3 = branch ? gt3w : gf3w;
  const float* b1 = branch ? gt1b : gf1b;
  const float* b2 = branch ? gt2b : gf2b;
  const float* b3 = branch ? gt3b : gf3b;
  const float* a1 = branch ? a1t : a1f;
  const float* a2 = branch ? a2t : a2f;
  const float* P = projw + (size_t)branch * 128 * 64;
  __shared__ float r1[128], cf[128], redsum[4];
  int t = threadIdx.x, lane = t & 63, wv = t >> 6;

  {
    float x1 = 0.f, x2 = 0.f;
    for (int i = t; i < N; i += 128) { x1 += a1[i]; x2 += a2[i]; }
#pragma unroll
    for (int off = 32; off > 0; off >>= 1) {
      x1 += __shfl_xor(x1, off);
      x2 += __shfl_xor(x2, off);
    }
    if (lane == 0) { redsum[wv * 2] = x1; redsum[wv * 2 + 1] = x2; }
  }
  __syncthreads();
  float s1 = redsum[0] + redsum[2];
  float s2 = redsum[1] + redsum[3];

  {
    float s = 0.f;
#pragma unroll 4
    for (int h = 0; h < 128; ++h) s += b1[h] * W2[(size_t)h * 128 + t];
    r1[t] = s;
  }
  __syncthreads();
  {
    float sa = 0.f, sb = 0.f;
#pragma unroll 4
    for (int h = 0; h < 128; ++h) {
      float w3v = W3[(size_t)h * 128 + t];
      sa += r1[h] * w3v;
      sb += b2[h] * w3v;
    }
    cf[t] = (s2 * sa + s1 * sb) * (1.0f / N) + b3[t];
  }
  __syncthreads();
  if (t < 64) {
    float s = 0.f;
#pragma unroll 4
    for (int h = 0; h < 128; ++h) s += cf[h] * P[(size_t)h * 64 + t];
    cb[branch * 64 + t] = s;
  }
}

// ------- final: out[b] = (uf'XF[b])Qf + (ut'Xt[b])Qt + pb + cb_f + cb_t -------
__global__ __launch_bounds__(256) void gcn_out(
    const __hip_bfloat16* __restrict__ XF, const __hip_bfloat16* __restrict__ Xt,
    const float* __restrict__ uf, const float* __restrict__ ut,
    const float* __restrict__ Qf, const float* __restrict__ Qt,
    const float* __restrict__ cb, const float* __restrict__ pb,
    float* __restrict__ out)
{
  __shared__ float red[2048];
  __shared__ float yfL[256], ytL[128], red3[4][64];
  int b = blockIdx.x, t = threadIdx.x;

  {
    int rr = t >> 5, cc = t & 31;
    const __hip_bfloat16* base = XF + (size_t)b * 32768;
    float acc[8] = {};
    for (int it = 0; it < 16; ++it) {
      int row = it * 8 + rr;
      float uw = uf[row];
      uint4 v = *(const uint4*)(base + (size_t)row * 256 + cc * 8);
      unsigned arr[4] = {v.x, v.y, v.z, v.w};
#pragma unroll
      for (int q = 0; q < 4; ++q) {
        acc[2 * q] += uw * bf2f((unsigned short)(arr[q] & 0xffff));
        acc[2 * q + 1] += uw * bf2f((unsigned short)(arr[q] >> 16));
      }
    }
#pragma unroll
    for (int j = 0; j < 8; ++j) red[rr * 256 + cc * 8 + j] = acc[j];
  }
  __syncthreads();
  {
    float s = 0.f;
#pragma unroll
    for (int g = 0; g < 8; ++g) s += red[g * 256 + t];
    yfL[t] = s;
  }
  __syncthreads();
  {
    int rr = t >> 4, cc = t & 15;
    const __hip_bfloat16* base = Xt + (size_t)b * 32768;
    float acc[8] = {};
    for (int it = 0; it < 16; ++it) {
      int row = it * 16 + rr;
      float uw = ut[row];
      uint4 v = *(const uint4*)(base + (size_t)row * 128 + cc * 8);
      unsigned arr[4] = {v.x, v.y, v.z, v.w};
#pragma unroll
      for (int q = 0; q < 4; ++q) {
        acc[2 * q] += uw * bf2f((unsigned short)(arr[q] & 0xffff));
        acc[2 * q + 1] += uw * bf2f((unsigned short)(arr[q] >> 16));
      }
    }
#pragma unroll
    for (int j = 0; j < 8; ++j) red[rr * 128 + cc * 8 + j] = acc[j];
  }
  __syncthreads();
  if (t < 128) {
    float s = 0.f;
#pragma unroll
    for (int g = 0; g < 16; ++g) s += red[g * 128 + t];
    ytL[t] = s;
  }
  __syncthreads();
  {
    int grp = t >> 6, o = t & 63;
    float s = 0.f;
    for (int jj = 0; jj < 64; ++jj) {
      int j = grp * 64 + jj;
      s += yfL[j] * Qf[(size_t)j * 64 + o];
    }
    for (int jj = 0; jj < 32; ++jj) {
      int j = grp * 32 + jj;
      s += ytL[j] * Qt[(size_t)j * 64 + o];
    }
    red3[grp][o] = s;
  }
  __syncthreads();
  if (t < 64) {
    out[(size_t)b * 64 + t] = red3[0][t] + red3[1][t] + red3[2][t] + red3[3][t] +
                              pb[t] + cb[t] + cb[64 + t];
  }
}

extern "C" void kernel_launch(void* const* d_in, const int* in_sizes, int n_in,
                              void* d_out, int out_size, void* d_ws, size_t ws_size,
                              hipStream_t stream)
{
  const float* X_time = (const float*)d_in[0];
  const float* conv_w = (const float*)d_in[1];
  const float* conv_b = (const float*)d_in[2];
  const float* wq_feat = (const float*)d_in[3];
  const float* wk_feat = (const float*)d_in[4];
  const float* wq_time = (const float*)d_in[5];
  const float* wk_time = (const float*)d_in[6];
  const float* gf1_w = (const float*)d_in[7];
  const float* gf1_b = (const float*)d_in[8];
  const float* gf2_w = (const float*)d_in[9];
  const float* gf2_b = (const float*)d_in[10];
  const float* gf3_w = (const float*)d_in[11];
  const float* gf3_b = (const float*)d_in[12];
  const float* gt1_w = (const float*)d_in[13];
  const float* gt1_b = (const float*)d_in[14];
  const float* gt2_w = (const float*)d_in[15];
  const float* gt2_b = (const float*)d_in[16];
  const float* gt3_w = (const float*)d_in[17];
  const float* gt3_b = (const float*)d_in[18];
  const float* proj_w = (const float*)d_in[19];
  const float* proj_b = (const float*)d_in[20];

  typedef __hip_bfloat16 bf16;
  char* ws = (char*)d_ws;
  const size_t MiB = 1ull << 20;
  bf16* XFb = (bf16*)ws;                         // 32MB
  bf16* Xtb = (bf16*)(ws + 34 * MiB);            // 32MB
  bf16* partial_f = (bf16*)(ws + 68 * MiB);      // 8MB
  bf16* partial_t = (bf16*)(ws + 100 * MiB);     // 16MB
  bf16* Xt = (bf16*)(ws + 100 * MiB);            // 32MB, conv-only
  float* l2f = (float*)(ws + 164 * MiB);         // 1MB
  float* l2t = (float*)(ws + 166 * MiB);         // 2MB
  char* SM = ws + 171 * MiB;
  float* A_feat = (float*)SM;                    // 64KB
  float* A_time = (float*)(SM + 65536);          // 256KB
  float* uf = (float*)(SM + 327680);
  float* ut = (float*)(SM + 328704);
  float* Qf = (float*)(SM + 331776);
  float* Qt = (float*)(SM + 397312);
  float* cb = (float*)(SM + 430080);
  bf16* Wcv = (bf16*)(SM + 432128);
  float* S3f = (float*)(SM + 530432);
  float* S3t = (float*)(SM + 563200);
  float* S2f = (float*)(SM + 595968);
  float* S2t = (float*)(SM + 628736);
  float* dis_f = (float*)(SM + 661504);
  float* dis_t = (float*)(SM + 662528);
  float* a1f = (float*)(SM + 663552);
  float* a1t = (float*)(SM + 664576);
  float* a2f = (float*)(SM + 665600);
  float* a2t = (float*)(SM + 666624);
  float* w1f = (float*)(SM + 667648);
  float* w1t = (float*)(SM + 668672);
  float* w2f = (float*)(SM + 669696);
  float* w2t = (float*)(SM + 670720);
  float* wdf = (float*)(SM + 671744);
  float* wdt = (float*)(SM + 672768);

  float* out = (float*)d_out;
  float* outA_f = out + 32768;
  float* outA_t = out + 49152;

  // 1) prep (merged wc_cast) + conv
  prep_wc<<<16384 + 192, 256, 0, stream>>>(X_time, Xtb, Xt, conv_w, Wcv);
  conv_gemm<<<dim3(2, NB), 256, 0, stream>>>(Xt, Wcv, conv_b, XFb);
  // 2) both grams in ONE 512-block dispatch (tail-packing across feat/time)
  gram_both<<<512, 512, 0, stream>>>(XFb, wq_feat, wk_feat, partial_f,
                                     Xtb, wq_time, wk_time, partial_t);
  // 3) finalize A: merged hierarchical reductions
  reduce_g2<<<384, 256, 0, stream>>>(partial_f, partial_t, l2f, l2t);
  A_fin2<<<80, 256, 0, stream>>>(l2f, l2t, A_feat, A_time, outA_f, outA_t);
  // 4) parallel vector chain + Q-chain + bias fold
  deg_both<<<6, 256, 0, stream>>>(A_feat, A_time, dis_f, dis_t);
  mv_both<<<96, 256, 0, stream>>>(A_feat, A_time, dis_f, dis_t, dis_f, dis_t,
                                  a1f, a1t, w1f, w1t, 0);
  mv_both<<<96, 256, 0, stream>>>(A_feat, A_time, w1f, w1t, dis_f, dis_t,
                                  a2f, a2t, w2f, w2t, 0);
  mv_both<<<96, 256, 0, stream>>>(A_feat, A_time, w2f, w2t, dis_f, dis_t,
                                  uf, ut, wdf, wdt, 1);
  qchain<<<dim3(32, 2), 256, 0, stream>>>(gf3_w, gt3_w, proj_w, proj_w + 8192,
                                          S3f, S3t, 128, 128);
  qchain<<<dim3(32, 2), 256, 0, stream>>>(gf2_w, gt2_w, S3f, S3t, S2f, S2t, 128, 128);
  qchain<<<dim3(64, 2), 256, 0, stream>>>(gf1_w, gt1_w, S2f, S2t, Qf, Qt, 256, 128);
  bias_fold<<<2, 128, 0, stream>>>(gf1_b, gf2_w, gf2_b, gf3_w, gf3_b,
                                   gt1_b, gt2_w, gt2_b, gt3_w, gt3_b,
                                   proj_w, a1f, a1t, a2f, a2t, cb);
  // 5) per-batch output
  gcn_out<<<NB, 256, 0, stream>>>(XFb, Xtb, uf, ut, Qf, Qt, cb, proj_b, out);
}